// Round 9
// baseline (122.813 us; speedup 1.0000x reference)
//
#include <hip/hip_runtime.h>
#include <math.h>

// KAN layer forward, MI355X.
// NUM_IN = NUM_OUT = 128, SIZE = 16384, BATCH = 512, K = 3 (cubic), G = 5.
//
// Reference semantics:
//   s = o*128 + i ;  pre_acts[s,b]   = x[b,i]
//   post_splines[s,b] = mask[s] * sum_j coef[s,j] * B3_j(x[b,i]; grid_s)
//   post_acts[s,b]    = scale_b[s]*silu(x[b,i]) + scale_spline[s]*post_splines[s,b]
//   y[b,i] = sum_o post_acts[o*128+i, b]
// Outputs concatenated: y (512*128), pre_acts.T, post_splines.T, post_acts.T
// (each 512*16384, layout [b][s]).
//
// v9 = v8 (121.2 us: LDS coef stride-9, wave-uniform fast path, plain
// stores, 2048 blocks) + ONE mechanism change in the y-reduction tail:
//   - each thread plain-stores its 4 y-partials to ws[oc][b][i] (coalesced,
//     8 MB, L2-resident) and a tiny second kernel sums the 32 oc-partials.
//     Removes all 2M device-scope atomicAdds AND the hipMemsetAsync
//     dispatch. Falls back to the v8 atomic path if ws_size < 8 MB.
//   - v5's earlier anti-atomic attempt was confounded (serialized loads,
//     split wave stores); this one changes ONLY the tail.
// History: v3b inner-loop global coef gathers regressed (TA choke);
// v6 NT-store ablation won; v7 basis hoisting won; v8 LDS coef neutral.

#define N_IN   128
#define SIZEK  16384
#define BATCH  512

#define TB 4    // batches per thread
#define CO 4    // o-values per thread
#define CPAD 9  // padded coef row stride in LDS (gcd(9,32)=1 -> conflict-free)

template <bool USE_WS>
__global__ __launch_bounds__(256) void kan_fwd(
    const float* __restrict__ x,            // [512][128]
    const float* __restrict__ scale_b,      // [16384]
    const float* __restrict__ scale_spline, // [16384]
    const float* __restrict__ coef,         // [16384][8]
    const float* __restrict__ mask,         // [16384]
    const float* __restrict__ knots,        // [16384][6]
    float* __restrict__ y,                  // [512][128] (pre-zeroed if !USE_WS)
    float* __restrict__ ws,                 // [32][512][128] partials (USE_WS)
    float* __restrict__ pre_out,            // [512][16384]
    float* __restrict__ spl_out,            // [512][16384]
    float* __restrict__ post_out)           // [512][16384]
{
    __shared__ float shc[512 * CPAD];       // 18432 B -> still 8 blocks/CU

    const int tid = threadIdx.x;
    const int g  = blockIdx.x * 256 + tid;
    const int i  = g & 127;          // input index (lane-consecutive -> coalesced)
    const int r  = g >> 7;           // [0, 4096)
    const int oc = r >> 7;           // o-chunk id, BLOCK-UNIFORM (32 chunks of 4 o)
    const int bg = r & 127;          // batch-group id (128 groups of 4)
    const int o0 = oc << 2;
    const int b0 = bg << 2;
    const int s_base = o0 << 7;      // first of the block's 512 consecutive s-rows

    // ---- stage the block's coef rows into LDS (coalesced float4 reads,
    //      padded-stride b32 writes). One-time cost per block.
    {
        const float4* src = (const float4*)(coef + (size_t)s_base * 8); // 1024 vec4
#pragma unroll
        for (int k = 0; k < 4; ++k) {
            const int f4  = k * 256 + tid;        // [0,1024)
            const float4 v = src[f4];
            const int row = f4 >> 1;              // [0,512)
            const int col = (f4 & 1) << 2;        // 0 or 4
            float* d = &shc[row * CPAD + col];
            d[0] = v.x; d[1] = v.y; d[2] = v.z; d[3] = v.w;
        }
    }

    float xv[TB], sil[TB], ysum[TB];
#pragma unroll
    for (int t = 0; t < TB; ++t) {
        const float xx = x[(b0 + t) * N_IN + i];
        xv[t]   = xx;
        sil[t]  = xx / (1.0f + __expf(-xx));   // silu(x) = x * sigmoid(x)
        ysum[t] = 0.0f;
    }

    // ---- prefetch per-edge scalars for the CO rows (independent loads)
    float e0v[CO], ihv[CO], mkv[CO], sbv[CO], ssv[CO];
#pragma unroll
    for (int oo = 0; oo < CO; ++oo) {
        const int s = ((o0 + oo) << 7) | i;
        const float k0 = knots[s * 6];
        const float k5 = knots[s * 6 + 5];
        const float h  = (k5 - k0) * 0.2f;     // (g_last-g_first)/G, G=5
        ihv[oo] = 1.0f / h;
        e0v[oo] = k0 - 3.0f * h;               // leftmost extended knot
        mkv[oo] = mask[s];
        sbv[oo] = scale_b[s];
        ssv[oo] = scale_spline[s];
    }

    __syncthreads();                 // coef staging complete (uniform barrier)

    // wave-uniform check: do all 4 rows share the same (e0, invh)?
    const bool same_lane =
        (e0v[1] == e0v[0]) && (ihv[1] == ihv[0]) &&
        (e0v[2] == e0v[0]) && (ihv[2] == ihv[0]) &&
        (e0v[3] == e0v[0]) && (ihv[3] == ihv[0]);

    if (__all(same_lane)) {
        // ======== FAST PATH: basis hoisted across the CO o-chunks ========
        const float e0   = e0v[0];
        const float invh = ihv[0];
#pragma unroll
        for (int t = 0; t < TB; ++t) {
            const float u  = (xv[t] - e0) * invh;
            const float mf = floorf(u);
            const int   m  = (int)mf;
            const float tt = u - mf;
            const bool inr = (m >= 0) && (m <= 10);

            const float t2  = tt * tt;
            const float t3  = t2 * tt;
            const float omt = 1.0f - tt;
            float w[4];
            w[0] = omt * omt * omt * (1.0f / 6.0f);
            w[1] = (3.0f * t3 - 6.0f * t2 + 4.0f) * (1.0f / 6.0f);
            w[2] = (-3.0f * t3 + 3.0f * t2 + 3.0f * tt + 1.0f) * (1.0f / 6.0f);
            w[3] = t3 * (1.0f / 6.0f);

            // masked weights + clamped select indices, once per t
            const int jlo = m - 3;
            int   jc[4];
            float wv[4];
#pragma unroll
            for (int rr = 0; rr < 4; ++rr) {
                const int j = jlo + rr;
                jc[rr] = min(max(j, 0), 7);
                wv[rr] = (inr && j >= 0 && j <= 7) ? w[rr] : 0.0f;
            }

#pragma unroll
            for (int oo = 0; oo < CO; ++oo) {
                const int s = ((o0 + oo) << 7) | i;
                const float* __restrict__ cs = &shc[(oo * 128 + i) * CPAD];

                float spline = 0.0f;
#pragma unroll
                for (int rr = 0; rr < 4; ++rr)
                    spline = fmaf(cs[jc[rr]], wv[rr], spline);  // ds_read_b32

                const float splm = spline * mkv[oo];
                const float post = fmaf(sbv[oo], sil[t], ssv[oo] * splm);

                const size_t idx = (size_t)(b0 + t) * SIZEK + (size_t)s;
                pre_out[idx]  = xv[t];
                spl_out[idx]  = splm;
                post_out[idx] = post;
                ysum[t] += post;
            }
        }
    } else {
        // ======== SLOW PATH: per-oo basis (general knots), LDS coef ========
#pragma unroll
        for (int oo = 0; oo < CO; ++oo) {
            const int s = ((o0 + oo) << 7) | i;
            const float e0   = e0v[oo];
            const float invh = ihv[oo];
            const float mk   = mkv[oo];
            const float sb   = sbv[oo];
            const float ss   = ssv[oo];
            const float* __restrict__ cs = &shc[(oo * 128 + i) * CPAD];

#pragma unroll
            for (int t = 0; t < TB; ++t) {
                const float u  = (xv[t] - e0) * invh;
                const float mf = floorf(u);
                const int   m  = (int)mf;
                const float tt = u - mf;
                const bool inr = (m >= 0) && (m <= 10);

                const float t2  = tt * tt;
                const float t3  = t2 * tt;
                const float omt = 1.0f - tt;
                float w[4];
                w[0] = omt * omt * omt * (1.0f / 6.0f);
                w[1] = (3.0f * t3 - 6.0f * t2 + 4.0f) * (1.0f / 6.0f);
                w[2] = (-3.0f * t3 + 3.0f * t2 + 3.0f * tt + 1.0f) * (1.0f / 6.0f);
                w[3] = t3 * (1.0f / 6.0f);

                const int jlo = m - 3;
                float spline = 0.0f;
#pragma unroll
                for (int rr = 0; rr < 4; ++rr) {
                    const int j   = jlo + rr;
                    const int jcr = min(max(j, 0), 7);
                    const float wvv = (inr && j >= 0 && j <= 7) ? w[rr] : 0.0f;
                    spline = fmaf(cs[jcr], wvv, spline);
                }

                const float splm = spline * mk;
                const float post = fmaf(sb, sil[t], ss * splm);

                const size_t idx = (size_t)(b0 + t) * SIZEK + (size_t)s;
                pre_out[idx]  = xv[t];
                spl_out[idx]  = splm;
                post_out[idx] = post;
                ysum[t] += post;
            }
        }
    }

    if (USE_WS) {
        // plain coalesced partial stores: ws[oc][b][i]; L2-resident (8 MB)
#pragma unroll
        for (int t = 0; t < TB; ++t)
            ws[((size_t)oc * BATCH + (b0 + t)) * N_IN + i] = ysum[t];
    } else {
#pragma unroll
        for (int t = 0; t < TB; ++t)
            atomicAdd(&y[(b0 + t) * N_IN + i], ysum[t]);
    }
}

// y[e] = sum_{oc=0}^{31} ws[oc][e], e = b*128+i. Reads 8 MB (L2-hot),
// writes 256 KB. 256 blocks x 256 threads, 1 element/thread.
__global__ __launch_bounds__(256) void kan_reduce(
    const float* __restrict__ ws, float* __restrict__ y)
{
    const int e = blockIdx.x * 256 + threadIdx.x;   // [0, 65536)
    float a = 0.0f;
#pragma unroll
    for (int oc = 0; oc < 32; ++oc)
        a += ws[(size_t)oc * (BATCH * N_IN) + e];
    y[e] = a;
}

extern "C" void kernel_launch(void* const* d_in, const int* in_sizes, int n_in,
                              void* d_out, int out_size, void* d_ws, size_t ws_size,
                              hipStream_t stream) {
    const float* x            = (const float*)d_in[0];
    const float* scale_b      = (const float*)d_in[1];
    const float* scale_spline = (const float*)d_in[2];
    const float* coef         = (const float*)d_in[3];
    const float* mask         = (const float*)d_in[4];
    const float* knots        = (const float*)d_in[5];

    float* out  = (float*)d_out;
    float* y    = out;                         // 512*128      = 65536
    float* pre  = y + 512 * 128;               // 512*16384    = 8388608
    float* spl  = pre + (size_t)512 * 16384;
    float* post = spl + (size_t)512 * 16384;

    const size_t need = (size_t)32 * BATCH * N_IN * sizeof(float);  // 8 MB
    dim3 grid(2048), block(256);

    if (d_ws != nullptr && ws_size >= need) {
        // no memset, no atomics: partials -> ws, then tiny reduce kernel
        float* ws = (float*)d_ws;
        kan_fwd<true><<<grid, block, 0, stream>>>(x, scale_b, scale_spline,
                                                  coef, mask, knots, y, ws,
                                                  pre, spl, post);
        kan_reduce<<<dim3(256), block, 0, stream>>>(ws, y);
    } else {
        // fallback: v8 atomic path (y pre-zeroed; harness poisons d_out)
        (void)hipMemsetAsync(y, 0, BATCH * N_IN * sizeof(float), stream);
        kan_fwd<false><<<grid, block, 0, stream>>>(x, scale_b, scale_spline,
                                                   coef, mask, knots, y, nullptr,
                                                   pre, spl, post);
    }
}